// Round 9
// baseline (1002.855 us; speedup 1.0000x reference)
//
#include <hip/hip_runtime.h>
#include <math.h>

// Residual VQ matching a float32 numpy reference (R3/R6/R7-verified semantics):
//   scores = x2 + e2 - 2*(res @ emb.T) in f32, argmin = first-min.
// R9: bf16x3 MFMA hot path; counted-vmcnt LDS pipeline (dist-2) + NEW:
//   depth-2 kk register prefetch (3-slot rotation), 4 blocks/CU, setprio
//   around MFMA cluster, e2 folded into acc init (score = -2*acc).
//   Margin-flagged rows -> exact replicated-f32 fixup kernel.

#define D_DIM 128
#define K_CB  1024
#define L_LVL 4
#define LK    (L_LVL * K_CB)
#define LKD   (LK * D_DIM)
#define NT    32
#define MARGIN_ACC 1.25e-4f   // score-domain 2.5e-4 (~40 sigma of 3-pass err)

typedef __bf16 bf16x8 __attribute__((ext_vector_type(8)));
typedef float  f32x16 __attribute__((ext_vector_type(16)));

// force f32 rounding of a product (blocks fma contraction)
static __device__ __forceinline__ float mulr(float a, float b) {
    float p = a * b; asm volatile("" : "+v"(p)); return p;
}

// ---------------- prep: bf16 hi/lo split + pairwise e2 + flag zero ----------------
__global__ void rvq_prep(const float* __restrict__ cb,
                         __bf16* __restrict__ hi, __bf16* __restrict__ lo,
                         float* __restrict__ e2p, unsigned* __restrict__ flagcnt) {
    int i = blockIdx.x * blockDim.x + threadIdx.x;   // over LKD/4
    if (i == 0) *flagcnt = 0;
    float4 v = ((const float4*)cb)[i];
    float f[4] = {v.x, v.y, v.z, v.w};
    #pragma unroll
    for (int e = 0; e < 4; ++e) {
        __bf16 h = (__bf16)f[e];
        hi[i * 4 + e] = h;
        lo[i * 4 + e] = (__bf16)(f[e] - (float)h);
    }
    if ((i & 31) == 0) {     // one lane per codeword row: numpy-pairwise ||e||^2
        int row = i >> 5;
        const float* ep = cb + (size_t)row * D_DIM;
        float r8[8];
        #pragma unroll
        for (int j = 0; j < 8; ++j) r8[j] = mulr(ep[j], ep[j]);
        #pragma unroll
        for (int b = 1; b < 16; ++b)
            #pragma unroll
            for (int j = 0; j < 8; ++j) r8[j] += mulr(ep[b * 8 + j], ep[b * 8 + j]);
        e2p[row] = ((r8[0] + r8[1]) + (r8[2] + r8[3])) + ((r8[4] + r8[5]) + (r8[6] + r8[7]));
    }
}

// ---------------- stage one 32-codeword tile (hi+lo) into LDS ----------------
static __device__ __forceinline__ void stage_tile(
    const __bf16* cbhL, const __bf16* cblL, int t,
    __bf16* dsth, __bf16* dstl, int wave, int lane) {
    const int k0 = t * 32;
    const size_t off = (size_t)(k0 + (lane & 31)) * D_DIM + (lane >> 5) * 8;
    #pragma unroll
    for (int c = 0; c < 2; ++c) {
        const int it = wave * 2 + c;
        __builtin_amdgcn_global_load_lds(
            (const __attribute__((address_space(1))) void*)(cbhL + off + it * 16),
            (__attribute__((address_space(3))) void*)(dsth + it * 512), 16, 0, 0);
        __builtin_amdgcn_global_load_lds(
            (const __attribute__((address_space(1))) void*)(cblL + off + it * 16),
            (__attribute__((address_space(3))) void*)(dstl + it * 512), 16, 0, 0);
    }
}

// ---------------- MFMA hot kernel ----------------
__global__ __launch_bounds__(256, 4)
void rvq_mfma(const float* __restrict__ residual,
              const float* __restrict__ codebooks,
              const __bf16* __restrict__ cbh, const __bf16* __restrict__ cbl,
              const float* __restrict__ e2p,
              unsigned* __restrict__ flagcnt, unsigned* __restrict__ flaglist,
              unsigned flagcap, float* __restrict__ out, int B) {
    __shared__ __align__(16) __bf16 bufh[2][32 * D_DIM];   // 16 KB
    __shared__ __align__(16) __bf16 bufl[2][32 * D_DIM];   // 16 KB
    __shared__ float e2s[K_CB];                            // 4 KB (current level)
    __shared__ int   bidxs[L_LVL][128];
    __shared__ unsigned char flg[128];

    const int tid  = threadIdx.x;
    const int wave = tid >> 6;
    const int lane = tid & 63;
    const int col  = lane & 31;
    const int h    = lane >> 5;
    const int rb   = wave * 32;
    const int grow = blockIdx.x * 128 + rb + col;

    if (tid < 128) flg[tid] = 0;

    // A fragments: residual row split to bf16 hi/lo, in registers.
    bf16x8 Ah[8], Al[8];
    {
        const float* rowp = residual + (size_t)grow * D_DIM;
        #pragma unroll
        for (int kk = 0; kk < 8; ++kk) {
            const int d0 = kk * 16 + h * 8;
            float4 a = *(const float4*)(rowp + d0);
            float4 b = *(const float4*)(rowp + d0 + 4);
            float f[8] = {a.x, a.y, a.z, a.w, b.x, b.y, b.z, b.w};
            #pragma unroll
            for (int e = 0; e < 8; ++e) {
                __bf16 hh = (__bf16)f[e];
                Ah[kk][e] = hh;
                Al[kk][e] = (__bf16)(f[e] - (float)hh);
            }
        }
    }

    for (int l = 0; l < L_LVL; ++l) {
        const __bf16* cbhL = cbh + (size_t)l * K_CB * D_DIM;
        const __bf16* cblL = cbl + (size_t)l * K_CB * D_DIM;

        // drain stray vmem (A-build / previous level's gathers) so counted
        // vmcnt below sees only this level's staging loads.
        asm volatile("s_waitcnt vmcnt(0)" ::: "memory");

        // current level's e2 -> LDS (visible after tile-0 top barrier)
        ((float4*)e2s)[tid] = ((const float4*)(e2p + l * K_CB))[tid];

        float rbest[16], rbest2[16]; int ridx[16];
        #pragma unroll
        for (int s = 0; s < 16; ++s) { rbest[s] = -3.4e38f; rbest2[s] = -3.4e38f; ridx[s] = 0x7fffffff; }

        // distance-2 prologue: 8 staging loads in flight per wave
        stage_tile(cbhL, cblL, 0, &bufh[0][0], &bufl[0][0], wave, lane);
        stage_tile(cbhL, cblL, 1, &bufh[1][0], &bufl[1][0], wave, lane);

        for (int t = 0; t < NT; ++t) {
            const int cur = t & 1;
            if (t < NT - 1) asm volatile("s_waitcnt vmcnt(4) lgkmcnt(0)" ::: "memory");
            else            asm volatile("s_waitcnt vmcnt(0) lgkmcnt(0)" ::: "memory");
            __builtin_amdgcn_s_barrier();          // tile t resident in buf[cur]
            __builtin_amdgcn_sched_barrier(0);

            const __bf16* bh = &bufh[cur][0];
            const __bf16* bl = &bufl[cur][0];

            // acc init folds e2: score = e2 - 2*dot = -2 * acc_final
            const float e2i = -0.5f * e2s[t * 32 + col];
            f32x16 accA, accB;
            #pragma unroll
            for (int s = 0; s < 16; ++s) { accA[s] = e2i; accB[s] = 0.f; }

            // depth-2 kk register prefetch, 3-slot rotation
            bf16x8 Bh[3], Bl[3];
            Bh[0] = *(const bf16x8*)(bh + 0 * 512 + lane * 8);
            Bl[0] = *(const bf16x8*)(bl + 0 * 512 + lane * 8);
            Bh[1] = *(const bf16x8*)(bh + 1 * 512 + lane * 8);
            Bl[1] = *(const bf16x8*)(bl + 1 * 512 + lane * 8);

            __builtin_amdgcn_s_setprio(1);
            #pragma unroll
            for (int kk = 0; kk < 8; ++kk) {
                const int sl = kk % 3;
                if (kk < 6) {
                    const int pl = (kk + 2) % 3;
                    Bh[pl] = *(const bf16x8*)(bh + (kk + 2) * 512 + lane * 8);
                    Bl[pl] = *(const bf16x8*)(bl + (kk + 2) * 512 + lane * 8);
                }
                if (kk & 1) {
                    accB = __builtin_amdgcn_mfma_f32_32x32x16_bf16(Ah[kk], Bh[sl], accB, 0, 0, 0);
                    accB = __builtin_amdgcn_mfma_f32_32x32x16_bf16(Ah[kk], Bl[sl], accB, 0, 0, 0);
                    accB = __builtin_amdgcn_mfma_f32_32x32x16_bf16(Al[kk], Bh[sl], accB, 0, 0, 0);
                } else {
                    accA = __builtin_amdgcn_mfma_f32_32x32x16_bf16(Ah[kk], Bh[sl], accA, 0, 0, 0);
                    accA = __builtin_amdgcn_mfma_f32_32x32x16_bf16(Ah[kk], Bl[sl], accA, 0, 0, 0);
                    accA = __builtin_amdgcn_mfma_f32_32x32x16_bf16(Al[kk], Bh[sl], accA, 0, 0, 0);
                }
            }
            __builtin_amdgcn_s_setprio(0);

            __builtin_amdgcn_sched_barrier(0);
            __builtin_amdgcn_s_barrier();          // all waves done reading buf[cur]
            asm volatile("" ::: "memory");
            if (t + 2 < NT)
                stage_tile(cbhL, cblL, t + 2, &bufh[cur][0], &bufl[cur][0], wave, lane);

            // top-2 in MAX domain (acc = dot - e2/2; bigger = better)
            const int k = t * 32 + col;
            #pragma unroll
            for (int s = 0; s < 16; ++s) {
                float sc = accA[s] + accB[s];
                if (sc > rbest[s])       { rbest2[s] = rbest[s]; rbest[s] = sc; ridx[s] = k; }
                else if (sc > rbest2[s]) { rbest2[s] = sc; }
            }
        }

        // merge top-2 (max domain) across the 32 cols; first-max (lowest k) wins
        #pragma unroll
        for (int s = 0; s < 16; ++s) {
            float b = rbest[s], b2 = rbest2[s]; int ix = ridx[s];
            #pragma unroll
            for (int m = 1; m <= 16; m <<= 1) {
                float bo  = __shfl_xor(b,  m, 64);
                float b2o = __shfl_xor(b2, m, 64);
                int   io  = __shfl_xor(ix, m, 64);
                float nb2 = fmaxf(fminf(b, bo), fmaxf(b2, b2o));
                if (bo > b || (bo == b && io < ix)) { b = bo; ix = io; }
                b2 = nb2;
            }
            const int rloc = (s & 3) + 8 * (s >> 2) + 4 * h;   // verified C row map
            if (col == 0) {
                bidxs[l][rb + rloc] = ix;
                if (b - b2 <= MARGIN_ACC) flg[rb + rloc] = 1;
            }
        }
        __syncthreads();

        // residual update in f32, re-split to bf16 pair (drift << margin budget)
        {
            const int bi = bidxs[l][rb + col];
            const float* qp = codebooks + ((size_t)l * K_CB + bi) * D_DIM;
            #pragma unroll
            for (int kk = 0; kk < 8; ++kk) {
                const int d0 = kk * 16 + h * 8;
                float4 qa = *(const float4*)(qp + d0);
                float4 qb = *(const float4*)(qp + d0 + 4);
                float q[8] = {qa.x, qa.y, qa.z, qa.w, qb.x, qb.y, qb.z, qb.w};
                #pragma unroll
                for (int e = 0; e < 8; ++e) {
                    float r = ((float)Ah[kk][e] + (float)Al[kk][e]) - q[e];
                    __bf16 hh = (__bf16)r;
                    Ah[kk][e] = hh;
                    Al[kk][e] = (__bf16)(r - (float)hh);
                }
            }
        }
    }

    // quantized = r0 - r_final
    {
        const float* rowp = residual + (size_t)grow * D_DIM;
        float* op = out + (size_t)grow * D_DIM;
        #pragma unroll
        for (int kk = 0; kk < 8; ++kk) {
            const int d0 = kk * 16 + h * 8;
            float4 a = *(const float4*)(rowp + d0);
            float4 b = *(const float4*)(rowp + d0 + 4);
            float f[8] = {a.x, a.y, a.z, a.w, b.x, b.y, b.z, b.w};
            float o[8];
            #pragma unroll
            for (int e = 0; e < 8; ++e)
                o[e] = f[e] - ((float)Ah[kk][e] + (float)Al[kk][e]);
            *(float4*)(op + d0)     = make_float4(o[0], o[1], o[2], o[3]);
            *(float4*)(op + d0 + 4) = make_float4(o[4], o[5], o[6], o[7]);
        }
    }
    if (tid < 128) {
        int row = blockIdx.x * 128 + tid;
        float4* cp = (float4*)(out + (size_t)B * D_DIM + (size_t)row * L_LVL);
        *cp = make_float4((float)bidxs[0][tid], (float)bidxs[1][tid],
                          (float)bidxs[2][tid], (float)bidxs[3][tid]);
        if (flg[tid]) {
            unsigned pos = atomicAdd(flagcnt, 1u);
            if (pos < flagcap) flaglist[pos] = row;
        }
    }
}

// ---------------- fixup: replicated reference semantics per flagged row ----------------
__global__ __launch_bounds__(256, 1)
void rvq_fixup(const float* __restrict__ residual,
               const float* __restrict__ codebooks,
               const float* __restrict__ e2p,
               const unsigned* __restrict__ flagcnt,
               const unsigned* __restrict__ flaglist,
               unsigned flagcap, float* __restrict__ out, int B) {
    __shared__ float rbuf[D_DIM];
    __shared__ float r0buf[D_DIM];
    __shared__ float x2s;
    __shared__ float redS[256];
    __shared__ int   redK[256];
    __shared__ int   codes_s[L_LVL];

    unsigned n = *flagcnt;
    if (n > flagcap) n = flagcap;

    for (unsigned b = blockIdx.x; b < n; b += gridDim.x) {
        int row = (int)flaglist[b];
        if (threadIdx.x < 32) {
            float4 v = ((const float4*)(residual + (size_t)row * D_DIM))[threadIdx.x];
            *(float4*)&rbuf[threadIdx.x * 4]  = v;
            *(float4*)&r0buf[threadIdx.x * 4] = v;
        }
        __syncthreads();

        for (int l = 0; l < L_LVL; ++l) {
            const float* cbl = codebooks + (size_t)l * K_CB * D_DIM;
            if (threadIdx.x == 0) {
                float r8[8];
                #pragma unroll
                for (int j = 0; j < 8; ++j) r8[j] = mulr(rbuf[j], rbuf[j]);
                for (int bb = 1; bb < 16; ++bb)
                    #pragma unroll
                    for (int j = 0; j < 8; ++j) r8[j] += mulr(rbuf[bb * 8 + j], rbuf[bb * 8 + j]);
                x2s = ((r8[0] + r8[1]) + (r8[2] + r8[3])) + ((r8[4] + r8[5]) + (r8[6] + r8[7]));
            }
            __syncthreads();
            float x2 = x2s;

            float bS = 3.4e38f;
            int   bK = 0x7fffffff;
            for (int m = 0; m < 4; ++m) {
                int k = threadIdx.x + m * 256;
                const float4* ek = (const float4*)(cbl + (size_t)k * D_DIM);
                double dd = 0.0;
                for (int c = 0; c < 32; ++c) {
                    float4 v = ek[c];
                    dd = fma((double)v.x, (double)rbuf[c * 4 + 0], dd);
                    dd = fma((double)v.y, (double)rbuf[c * 4 + 1], dd);
                    dd = fma((double)v.z, (double)rbuf[c * 4 + 2], dd);
                    dd = fma((double)v.w, (double)rbuf[c * 4 + 3], dd);
                }
                float M = (float)dd;                 // fl32(exact dot)
                float A = x2 + e2p[l * K_CB + k];    // fl32(x2 + e2)
                float S = A - 2.0f * M;              // final f32 rounding
                if (S < bS || (S == bS && k < bK)) { bS = S; bK = k; }
            }
            redS[threadIdx.x] = bS; redK[threadIdx.x] = bK;
            __syncthreads();
            for (int s = 128; s > 0; s >>= 1) {
                if (threadIdx.x < (unsigned)s) {
                    float So = redS[threadIdx.x + s];
                    int   Ko = redK[threadIdx.x + s];
                    if (So < redS[threadIdx.x] ||
                        (So == redS[threadIdx.x] && Ko < redK[threadIdx.x])) {
                        redS[threadIdx.x] = So; redK[threadIdx.x] = Ko;
                    }
                }
                __syncthreads();
            }
            int bi = redK[0];
            if (threadIdx.x == 0) codes_s[l] = bi;
            if (threadIdx.x < 32) {
                float4 q = ((const float4*)(cbl + (size_t)bi * D_DIM))[threadIdx.x];
                float4* p = (float4*)&rbuf[threadIdx.x * 4];
                float4 x = *p;
                x.x -= q.x; x.y -= q.y; x.z -= q.z; x.w -= q.w;
                *p = x;
            }
            __syncthreads();
        }

        if (threadIdx.x < 32) {
            float4 a = *(float4*)&r0buf[threadIdx.x * 4];
            float4 r = *(float4*)&rbuf[threadIdx.x * 4];
            ((float4*)(out + (size_t)row * D_DIM))[threadIdx.x] =
                make_float4(a.x - r.x, a.y - r.y, a.z - r.z, a.w - r.w);
        }
        if (threadIdx.x == 0) {
            float4* cp = (float4*)(out + (size_t)B * D_DIM + (size_t)row * L_LVL);
            *cp = make_float4((float)codes_s[0], (float)codes_s[1],
                              (float)codes_s[2], (float)codes_s[3]);
        }
        __syncthreads();
    }
}

extern "C" void kernel_launch(void* const* d_in, const int* in_sizes, int n_in,
                              void* d_out, int out_size, void* d_ws, size_t ws_size,
                              hipStream_t stream) {
    const float* residual  = (const float*)d_in[0];
    const float* codebooks = (const float*)d_in[1];
    float* out = (float*)d_out;
    int B = in_sizes[0] / D_DIM;  // 131072

    const size_t E2_BYTES = LK * sizeof(float);          // 16 KB
    const size_t CB_BYTES = (size_t)LKD * 2;             // 1 MB each (hi, lo)

    float*    e2p      = (float*)d_ws;
    __bf16*   cbh      = (__bf16*)((char*)d_ws + E2_BYTES);
    __bf16*   cblo     = (__bf16*)((char*)d_ws + E2_BYTES + CB_BYTES);
    unsigned* flagcnt  = (unsigned*)((char*)d_ws + E2_BYTES + 2 * CB_BYTES);
    unsigned* flaglist = flagcnt + 16;
    unsigned  flagcap  = (unsigned)((ws_size - (E2_BYTES + 2 * CB_BYTES + 64)) / 4);
    if (flagcap > (unsigned)B) flagcap = (unsigned)B;

    hipLaunchKernelGGL(rvq_prep, dim3(LKD / 4 / 256), dim3(256), 0, stream,
                       codebooks, cbh, cblo, e2p, flagcnt);
    hipLaunchKernelGGL(rvq_mfma, dim3(B / 128), dim3(256), 0, stream,
                       residual, codebooks, cbh, cblo, e2p,
                       flagcnt, flaglist, flagcap, out, B);
    hipLaunchKernelGGL(rvq_fixup, dim3(512), dim3(256), 0, stream,
                       residual, codebooks, e2p, flagcnt, flaglist, flagcap, out, B);
}

// Round 10
// 659.370 us; speedup vs baseline: 1.5209x; 1.5209x over previous
//
#include <hip/hip_runtime.h>
#include <math.h>

// Residual VQ matching a float32 numpy reference (R3/R6/R7/R9-verified):
//   scores = x2 + e2 - 2*(res @ emb.T) in f32, argmin = first-min.
// R10: bf16x3 MFMA hot path; 64-codeword super-tiles (2 x 32KB dbuf, half the
// barriers of R8), counted vmcnt(8) pipeline, setprio around 48-MFMA cluster,
// e2 folded into acc init (score = -2*acc, max-domain). launch_bounds(256,2)
// (R9 lesson: (256,4) forced 64 VGPRs -> 1.9GB spill traffic).
// Margin-flagged rows -> exact replicated-f32 fixup kernel.

#define D_DIM 128
#define K_CB  1024
#define L_LVL 4
#define LK    (L_LVL * K_CB)
#define LKD   (LK * D_DIM)
#define NT2   16              // 16 super-steps x 64 codewords
#define MARGIN_ACC 1.25e-4f   // score-domain 2.5e-4 (~40 sigma of 3-pass err)

typedef __bf16 bf16x8 __attribute__((ext_vector_type(8)));
typedef float  f32x16 __attribute__((ext_vector_type(16)));

// force f32 rounding of a product (blocks fma contraction)
static __device__ __forceinline__ float mulr(float a, float b) {
    float p = a * b; asm volatile("" : "+v"(p)); return p;
}

// ---------------- prep: bf16 hi/lo split + pairwise e2 + flag zero ----------------
__global__ void rvq_prep(const float* __restrict__ cb,
                         __bf16* __restrict__ hi, __bf16* __restrict__ lo,
                         float* __restrict__ e2p, unsigned* __restrict__ flagcnt) {
    int i = blockIdx.x * blockDim.x + threadIdx.x;   // over LKD/4
    if (i == 0) *flagcnt = 0;
    float4 v = ((const float4*)cb)[i];
    float f[4] = {v.x, v.y, v.z, v.w};
    #pragma unroll
    for (int e = 0; e < 4; ++e) {
        __bf16 h = (__bf16)f[e];
        hi[i * 4 + e] = h;
        lo[i * 4 + e] = (__bf16)(f[e] - (float)h);
    }
    if ((i & 31) == 0) {     // one lane per codeword row: numpy-pairwise ||e||^2
        int row = i >> 5;
        const float* ep = cb + (size_t)row * D_DIM;
        float r8[8];
        #pragma unroll
        for (int j = 0; j < 8; ++j) r8[j] = mulr(ep[j], ep[j]);
        #pragma unroll
        for (int b = 1; b < 16; ++b)
            #pragma unroll
            for (int j = 0; j < 8; ++j) r8[j] += mulr(ep[b * 8 + j], ep[b * 8 + j]);
        e2p[row] = ((r8[0] + r8[1]) + (r8[2] + r8[3])) + ((r8[4] + r8[5]) + (r8[6] + r8[7]));
    }
}

// ---------------- stage one 64-codeword super-tile (hi+lo) into LDS ----------------
// Pre-swizzled global source, linear LDS dest (m173 pattern): LDS chunk
// (s,kkc) holds rows s*32+(l&31), d-elems kkc*16+(l>>5)*8 — so the MFMA
// B-fragment read (sub*4096 + kk*512 + lane*8) is linear in lane (no conflicts).
static __device__ __forceinline__ void stage_super(
    const __bf16* cbhL, const __bf16* cblL, int t,
    __bf16* dsth, __bf16* dstl, int wave, int lane) {
    const size_t base = (size_t)t * 64 * D_DIM;
    #pragma unroll
    for (int c = 0; c < 4; ++c) {
        const int it  = wave * 4 + c;   // 0..15
        const int s   = it >> 3;        // sub-tile (32 rows)
        const int kkc = it & 7;         // d-chunk
        const size_t goff = base + (size_t)(s * 32 + (lane & 31)) * D_DIM
                          + kkc * 16 + (lane >> 5) * 8;
        const int loff = s * 4096 + kkc * 512;
        __builtin_amdgcn_global_load_lds(
            (const __attribute__((address_space(1))) void*)(cbhL + goff),
            (__attribute__((address_space(3))) void*)(dsth + loff), 16, 0, 0);
        __builtin_amdgcn_global_load_lds(
            (const __attribute__((address_space(1))) void*)(cblL + goff),
            (__attribute__((address_space(3))) void*)(dstl + loff), 16, 0, 0);
    }
}

// ---------------- MFMA hot kernel ----------------
__global__ __launch_bounds__(256, 2)
void rvq_mfma(const float* __restrict__ residual,
              const float* __restrict__ codebooks,
              const __bf16* __restrict__ cbh, const __bf16* __restrict__ cbl,
              const float* __restrict__ e2p,
              unsigned* __restrict__ flagcnt, unsigned* __restrict__ flaglist,
              unsigned flagcap, float* __restrict__ out, int B) {
    __shared__ __align__(16) __bf16 bufh[2][64 * D_DIM];   // 32 KB
    __shared__ __align__(16) __bf16 bufl[2][64 * D_DIM];   // 32 KB
    __shared__ float e2s[K_CB];                            // 4 KB (current level)
    __shared__ int   bidxs[L_LVL][128];
    __shared__ unsigned char flg[128];

    const int tid  = threadIdx.x;
    const int wave = tid >> 6;
    const int lane = tid & 63;
    const int col  = lane & 31;
    const int h    = lane >> 5;
    const int rb   = wave * 32;
    const int grow = blockIdx.x * 128 + rb + col;

    if (tid < 128) flg[tid] = 0;

    // A fragments: residual row split to bf16 hi/lo, in registers.
    bf16x8 Ah[8], Al[8];
    {
        const float* rowp = residual + (size_t)grow * D_DIM;
        #pragma unroll
        for (int kk = 0; kk < 8; ++kk) {
            const int d0 = kk * 16 + h * 8;
            float4 a = *(const float4*)(rowp + d0);
            float4 b = *(const float4*)(rowp + d0 + 4);
            float f[8] = {a.x, a.y, a.z, a.w, b.x, b.y, b.z, b.w};
            #pragma unroll
            for (int e = 0; e < 8; ++e) {
                __bf16 hh = (__bf16)f[e];
                Ah[kk][e] = hh;
                Al[kk][e] = (__bf16)(f[e] - (float)hh);
            }
        }
    }

    for (int l = 0; l < L_LVL; ++l) {
        const __bf16* cbhL = cbh + (size_t)l * K_CB * D_DIM;
        const __bf16* cblL = cbl + (size_t)l * K_CB * D_DIM;

        // current level's e2 -> LDS, then drain vmem so the counted-vmcnt
        // pipeline below sees ONLY its own staging loads.
        ((float4*)e2s)[tid] = ((const float4*)(e2p + l * K_CB))[tid];
        asm volatile("s_waitcnt vmcnt(0)" ::: "memory");

        float rbest[16], rbest2[16]; int ridx[16];
        #pragma unroll
        for (int s = 0; s < 16; ++s) { rbest[s] = -3.4e38f; rbest2[s] = -3.4e38f; ridx[s] = 0x7fffffff; }

        // distance-2 prologue: 16 staging loads in flight per wave
        stage_super(cbhL, cblL, 0, &bufh[0][0], &bufl[0][0], wave, lane);
        stage_super(cbhL, cblL, 1, &bufh[1][0], &bufl[1][0], wave, lane);

        for (int t = 0; t < NT2; ++t) {
            const int cur = t & 1;
            // oldest 8 outstanding = tile t's (FIFO) -> counted wait
            if (t < NT2 - 1) asm volatile("s_waitcnt vmcnt(8) lgkmcnt(0)" ::: "memory");
            else            asm volatile("s_waitcnt vmcnt(0) lgkmcnt(0)" ::: "memory");
            __builtin_amdgcn_s_barrier();          // tile t resident in buf[cur]
            __builtin_amdgcn_sched_barrier(0);

            const __bf16* bh = &bufh[cur][0];
            const __bf16* bl = &bufl[cur][0];

            // acc init folds e2: score = e2 - 2*dot = -2 * acc_final
            const float e2i0 = -0.5f * e2s[t * 64 + col];
            const float e2i1 = -0.5f * e2s[t * 64 + 32 + col];
            f32x16 accA0, accB0, accA1, accB1;
            #pragma unroll
            for (int s = 0; s < 16; ++s) {
                accA0[s] = e2i0; accB0[s] = 0.f;
                accA1[s] = e2i1; accB1[s] = 0.f;
            }

            __builtin_amdgcn_s_setprio(1);
            #pragma unroll
            for (int kk = 0; kk < 8; ++kk) {        // sub-tile 0 (cols t*64+0..31)
                bf16x8 Bh = *(const bf16x8*)(bh + kk * 512 + lane * 8);
                bf16x8 Bl = *(const bf16x8*)(bl + kk * 512 + lane * 8);
                if (kk & 1) {
                    accB0 = __builtin_amdgcn_mfma_f32_32x32x16_bf16(Ah[kk], Bh, accB0, 0, 0, 0);
                    accB0 = __builtin_amdgcn_mfma_f32_32x32x16_bf16(Ah[kk], Bl, accB0, 0, 0, 0);
                    accB0 = __builtin_amdgcn_mfma_f32_32x32x16_bf16(Al[kk], Bh, accB0, 0, 0, 0);
                } else {
                    accA0 = __builtin_amdgcn_mfma_f32_32x32x16_bf16(Ah[kk], Bh, accA0, 0, 0, 0);
                    accA0 = __builtin_amdgcn_mfma_f32_32x32x16_bf16(Ah[kk], Bl, accA0, 0, 0, 0);
                    accA0 = __builtin_amdgcn_mfma_f32_32x32x16_bf16(Al[kk], Bh, accA0, 0, 0, 0);
                }
            }
            #pragma unroll
            for (int kk = 0; kk < 8; ++kk) {        // sub-tile 1 (cols t*64+32..63)
                bf16x8 Bh = *(const bf16x8*)(bh + 4096 + kk * 512 + lane * 8);
                bf16x8 Bl = *(const bf16x8*)(bl + 4096 + kk * 512 + lane * 8);
                if (kk & 1) {
                    accB1 = __builtin_amdgcn_mfma_f32_32x32x16_bf16(Ah[kk], Bh, accB1, 0, 0, 0);
                    accB1 = __builtin_amdgcn_mfma_f32_32x32x16_bf16(Ah[kk], Bl, accB1, 0, 0, 0);
                    accB1 = __builtin_amdgcn_mfma_f32_32x32x16_bf16(Al[kk], Bh, accB1, 0, 0, 0);
                } else {
                    accA1 = __builtin_amdgcn_mfma_f32_32x32x16_bf16(Ah[kk], Bh, accA1, 0, 0, 0);
                    accA1 = __builtin_amdgcn_mfma_f32_32x32x16_bf16(Ah[kk], Bl, accA1, 0, 0, 0);
                    accA1 = __builtin_amdgcn_mfma_f32_32x32x16_bf16(Al[kk], Bh, accA1, 0, 0, 0);
                }
            }
            __builtin_amdgcn_s_setprio(0);

            __builtin_amdgcn_sched_barrier(0);
            __builtin_amdgcn_s_barrier();          // all waves done reading buf[cur]
            asm volatile("" ::: "memory");
            if (t + 2 < NT2)
                stage_super(cbhL, cblL, t + 2, &bufh[cur][0], &bufl[cur][0], wave, lane);

            // top-2 in MAX domain (acc = dot - e2/2; bigger = better)
            const int k0 = t * 64 + col;
            const int k1 = t * 64 + 32 + col;
            #pragma unroll
            for (int s = 0; s < 16; ++s) {
                float sc0 = accA0[s] + accB0[s];
                if (sc0 > rbest[s])       { rbest2[s] = rbest[s]; rbest[s] = sc0; ridx[s] = k0; }
                else if (sc0 > rbest2[s]) { rbest2[s] = sc0; }
                float sc1 = accA1[s] + accB1[s];
                if (sc1 > rbest[s])       { rbest2[s] = rbest[s]; rbest[s] = sc1; ridx[s] = k1; }
                else if (sc1 > rbest2[s]) { rbest2[s] = sc1; }
            }
        }

        // merge top-2 (max domain) across the 32 cols; first-max (lowest k) wins
        #pragma unroll
        for (int s = 0; s < 16; ++s) {
            float b = rbest[s], b2 = rbest2[s]; int ix = ridx[s];
            #pragma unroll
            for (int m = 1; m <= 16; m <<= 1) {
                float bo  = __shfl_xor(b,  m, 64);
                float b2o = __shfl_xor(b2, m, 64);
                int   io  = __shfl_xor(ix, m, 64);
                float nb2 = fmaxf(fminf(b, bo), fmaxf(b2, b2o));
                if (bo > b || (bo == b && io < ix)) { b = bo; ix = io; }
                b2 = nb2;
            }
            const int rloc = (s & 3) + 8 * (s >> 2) + 4 * h;   // verified C row map
            if (col == 0) {
                bidxs[l][rb + rloc] = ix;
                if (b - b2 <= MARGIN_ACC) flg[rb + rloc] = 1;
            }
        }
        __syncthreads();

        // residual update in f32, re-split to bf16 pair (drift << margin budget)
        {
            const int bi = bidxs[l][rb + col];
            const float* qp = codebooks + ((size_t)l * K_CB + bi) * D_DIM;
            #pragma unroll
            for (int kk = 0; kk < 8; ++kk) {
                const int d0 = kk * 16 + h * 8;
                float4 qa = *(const float4*)(qp + d0);
                float4 qb = *(const float4*)(qp + d0 + 4);
                float q[8] = {qa.x, qa.y, qa.z, qa.w, qb.x, qb.y, qb.z, qb.w};
                #pragma unroll
                for (int e = 0; e < 8; ++e) {
                    float r = ((float)Ah[kk][e] + (float)Al[kk][e]) - q[e];
                    __bf16 hh = (__bf16)r;
                    Ah[kk][e] = hh;
                    Al[kk][e] = (__bf16)(r - (float)hh);
                }
            }
        }
    }

    // quantized = r0 - r_final
    {
        const float* rowp = residual + (size_t)grow * D_DIM;
        float* op = out + (size_t)grow * D_DIM;
        #pragma unroll
        for (int kk = 0; kk < 8; ++kk) {
            const int d0 = kk * 16 + h * 8;
            float4 a = *(const float4*)(rowp + d0);
            float4 b = *(const float4*)(rowp + d0 + 4);
            float f[8] = {a.x, a.y, a.z, a.w, b.x, b.y, b.z, b.w};
            float o[8];
            #pragma unroll
            for (int e = 0; e < 8; ++e)
                o[e] = f[e] - ((float)Ah[kk][e] + (float)Al[kk][e]);
            *(float4*)(op + d0)     = make_float4(o[0], o[1], o[2], o[3]);
            *(float4*)(op + d0 + 4) = make_float4(o[4], o[5], o[6], o[7]);
        }
    }
    if (tid < 128) {
        int row = blockIdx.x * 128 + tid;
        float4* cp = (float4*)(out + (size_t)B * D_DIM + (size_t)row * L_LVL);
        *cp = make_float4((float)bidxs[0][tid], (float)bidxs[1][tid],
                          (float)bidxs[2][tid], (float)bidxs[3][tid]);
        if (flg[tid]) {
            unsigned pos = atomicAdd(flagcnt, 1u);
            if (pos < flagcap) flaglist[pos] = row;
        }
    }
}

// ---------------- fixup: replicated reference semantics per flagged row ----------------
__global__ __launch_bounds__(256, 1)
void rvq_fixup(const float* __restrict__ residual,
               const float* __restrict__ codebooks,
               const float* __restrict__ e2p,
               const unsigned* __restrict__ flagcnt,
               const unsigned* __restrict__ flaglist,
               unsigned flagcap, float* __restrict__ out, int B) {
    __shared__ float rbuf[D_DIM];
    __shared__ float r0buf[D_DIM];
    __shared__ float x2s;
    __shared__ float redS[256];
    __shared__ int   redK[256];
    __shared__ int   codes_s[L_LVL];

    unsigned n = *flagcnt;
    if (n > flagcap) n = flagcap;

    for (unsigned b = blockIdx.x; b < n; b += gridDim.x) {
        int row = (int)flaglist[b];
        if (threadIdx.x < 32) {
            float4 v = ((const float4*)(residual + (size_t)row * D_DIM))[threadIdx.x];
            *(float4*)&rbuf[threadIdx.x * 4]  = v;
            *(float4*)&r0buf[threadIdx.x * 4] = v;
        }
        __syncthreads();

        for (int l = 0; l < L_LVL; ++l) {
            const float* cbl = codebooks + (size_t)l * K_CB * D_DIM;
            if (threadIdx.x == 0) {
                float r8[8];
                #pragma unroll
                for (int j = 0; j < 8; ++j) r8[j] = mulr(rbuf[j], rbuf[j]);
                for (int bb = 1; bb < 16; ++bb)
                    #pragma unroll
                    for (int j = 0; j < 8; ++j) r8[j] += mulr(rbuf[bb * 8 + j], rbuf[bb * 8 + j]);
                x2s = ((r8[0] + r8[1]) + (r8[2] + r8[3])) + ((r8[4] + r8[5]) + (r8[6] + r8[7]));
            }
            __syncthreads();
            float x2 = x2s;

            float bS = 3.4e38f;
            int   bK = 0x7fffffff;
            for (int m = 0; m < 4; ++m) {
                int k = threadIdx.x + m * 256;
                const float4* ek = (const float4*)(cbl + (size_t)k * D_DIM);
                double dd = 0.0;
                for (int c = 0; c < 32; ++c) {
                    float4 v = ek[c];
                    dd = fma((double)v.x, (double)rbuf[c * 4 + 0], dd);
                    dd = fma((double)v.y, (double)rbuf[c * 4 + 1], dd);
                    dd = fma((double)v.z, (double)rbuf[c * 4 + 2], dd);
                    dd = fma((double)v.w, (double)rbuf[c * 4 + 3], dd);
                }
                float M = (float)dd;                 // fl32(exact dot)
                float A = x2 + e2p[l * K_CB + k];    // fl32(x2 + e2)
                float S = A - 2.0f * M;              // final f32 rounding
                if (S < bS || (S == bS && k < bK)) { bS = S; bK = k; }
            }
            redS[threadIdx.x] = bS; redK[threadIdx.x] = bK;
            __syncthreads();
            for (int s = 128; s > 0; s >>= 1) {
                if (threadIdx.x < (unsigned)s) {
                    float So = redS[threadIdx.x + s];
                    int   Ko = redK[threadIdx.x + s];
                    if (So < redS[threadIdx.x] ||
                        (So == redS[threadIdx.x] && Ko < redK[threadIdx.x])) {
                        redS[threadIdx.x] = So; redK[threadIdx.x] = Ko;
                    }
                }
                __syncthreads();
            }
            int bi = redK[0];
            if (threadIdx.x == 0) codes_s[l] = bi;
            if (threadIdx.x < 32) {
                float4 q = ((const float4*)(cbl + (size_t)bi * D_DIM))[threadIdx.x];
                float4* p = (float4*)&rbuf[threadIdx.x * 4];
                float4 x = *p;
                x.x -= q.x; x.y -= q.y; x.z -= q.z; x.w -= q.w;
                *p = x;
            }
            __syncthreads();
        }

        if (threadIdx.x < 32) {
            float4 a = *(float4*)&r0buf[threadIdx.x * 4];
            float4 r = *(float4*)&rbuf[threadIdx.x * 4];
            ((float4*)(out + (size_t)row * D_DIM))[threadIdx.x] =
                make_float4(a.x - r.x, a.y - r.y, a.z - r.z, a.w - r.w);
        }
        if (threadIdx.x == 0) {
            float4* cp = (float4*)(out + (size_t)B * D_DIM + (size_t)row * L_LVL);
            *cp = make_float4((float)codes_s[0], (float)codes_s[1],
                              (float)codes_s[2], (float)codes_s[3]);
        }
        __syncthreads();
    }
}

extern "C" void kernel_launch(void* const* d_in, const int* in_sizes, int n_in,
                              void* d_out, int out_size, void* d_ws, size_t ws_size,
                              hipStream_t stream) {
    const float* residual  = (const float*)d_in[0];
    const float* codebooks = (const float*)d_in[1];
    float* out = (float*)d_out;
    int B = in_sizes[0] / D_DIM;  // 131072

    const size_t E2_BYTES = LK * sizeof(float);          // 16 KB
    const size_t CB_BYTES = (size_t)LKD * 2;             // 1 MB each (hi, lo)

    float*    e2p      = (float*)d_ws;
    __bf16*   cbh      = (__bf16*)((char*)d_ws + E2_BYTES);
    __bf16*   cblo     = (__bf16*)((char*)d_ws + E2_BYTES + CB_BYTES);
    unsigned* flagcnt  = (unsigned*)((char*)d_ws + E2_BYTES + 2 * CB_BYTES);
    unsigned* flaglist = flagcnt + 16;
    unsigned  flagcap  = (unsigned)((ws_size - (E2_BYTES + 2 * CB_BYTES + 64)) / 4);
    if (flagcap > (unsigned)B) flagcap = (unsigned)B;

    hipLaunchKernelGGL(rvq_prep, dim3(LKD / 4 / 256), dim3(256), 0, stream,
                       codebooks, cbh, cblo, e2p, flagcnt);
    hipLaunchKernelGGL(rvq_mfma, dim3(B / 128), dim3(256), 0, stream,
                       residual, codebooks, cbh, cblo, e2p,
                       flagcnt, flaglist, flagcap, out, B);
    hipLaunchKernelGGL(rvq_fixup, dim3(512), dim3(256), 0, stream,
                       residual, codebooks, e2p, flagcnt, flaglist, flagcap, out, B);
}